// Round 1
// baseline (305.820 us; speedup 1.0000x reference)
//
#include <hip/hip_runtime.h>
#include <cmath>

#define BB 32
#define SS 2048
#define IND 300
#define HID 16
#define LAT 16
#define NA 64
#define NITER 20
#define GRAV 0.01f

// d_out layout (floats): field[32*16] | rec[32*2048*300] | masses[32] | change[1]
#define OFF_FIELD 0
#define OFF_REC   512
#define OFF_MASS  (512 + BB*SS*IND)
#define OFF_CHG   (OFF_MASS + BB)

// d_ws layout (floats)
#define WS_FIELD 0      // 512 accumulators
#define WS_CHG   512    // 1 accumulator
#define WS_REC   1024   // 9600 rec values

// ---------------------------------------------------------------------------
// Kernel 1: encoder + 20 gravity iterations + partial reductions.
// Thread-per-token (65536 threads). Attractor accesses are wave-uniform ->
// scalar loads; |att|^2 precomputed once per block into LDS.
// ---------------------------------------------------------------------------
__global__ __launch_bounds__(256, 1)
void k_enc_grav(const float* __restrict__ x, const float* __restrict__ w1,
                const float* __restrict__ b1, const float* __restrict__ w2,
                const float* __restrict__ b2, const float* __restrict__ att,
                float* __restrict__ ws)
{
    __shared__ float san[NA];
    if (threadIdx.x < NA) {
        const float* ar = att + threadIdx.x * LAT;
        float s = 0.f;
        #pragma unroll
        for (int j = 0; j < LAT; ++j) s = fmaf(ar[j], ar[j], s);
        san[threadIdx.x] = s;
    }

    const int token = blockIdx.x * 256 + threadIdx.x;

    // ---- encoder layer 1: h = relu(x @ w1 + b1) ----
    float h[HID];
    #pragma unroll
    for (int j = 0; j < HID; ++j) h[j] = b1[j];
    const float4* xr = (const float4*)(x + (size_t)token * IND);
    #pragma unroll 5
    for (int i4 = 0; i4 < IND / 4; ++i4) {
        float4 xv = xr[i4];
        const float* wr = w1 + i4 * 4 * HID;   // uniform -> s_load
        #pragma unroll
        for (int j = 0; j < HID; ++j) h[j] = fmaf(xv.x, wr[j],         h[j]);
        #pragma unroll
        for (int j = 0; j < HID; ++j) h[j] = fmaf(xv.y, wr[HID + j],   h[j]);
        #pragma unroll
        for (int j = 0; j < HID; ++j) h[j] = fmaf(xv.z, wr[2*HID + j], h[j]);
        #pragma unroll
        for (int j = 0; j < HID; ++j) h[j] = fmaf(xv.w, wr[3*HID + j], h[j]);
    }
    #pragma unroll
    for (int j = 0; j < HID; ++j) h[j] = fmaxf(h[j], 0.f);

    // ---- encoder layer 2: p = h @ w2 + b2 ----
    float p[LAT];
    #pragma unroll
    for (int d = 0; d < LAT; ++d) p[d] = b2[d];
    #pragma unroll
    for (int j = 0; j < HID; ++j) {
        const float* wr = w2 + j * LAT;        // uniform -> s_load
        #pragma unroll
        for (int d = 0; d < LAT; ++d) p[d] = fmaf(h[j], wr[d], p[d]);
    }

    __syncthreads();   // san ready

    // ---- gravity: dist^2 = |p|^2 + |a|^2 - 2 p.a ;  w = G/dist^2
    //      F = sum_a w*a  -  p * sum_a w ;  p += 0.1*F
    // ((sqrt(d2)+1e-6)^2 ~= d2 to 2e-6 rel: dist is O(2-4) always) ----
    float pn = 0.f;
    #pragma unroll
    for (int d = 0; d < LAT; ++d) pn = fmaf(p[d], p[d], pn);

    float cd = 0.f;    // squared change at last iteration
    for (int it = 0; it < NITER; ++it) {
        float F[LAT];
        #pragma unroll
        for (int d = 0; d < LAT; ++d) F[d] = 0.f;
        float wsum = 0.f;
        #pragma unroll 4
        for (int a = 0; a < NA; ++a) {
            const float* ar = att + a * LAT;   // uniform -> s_load_dwordx16
            float s0 = 0.f, s1 = 0.f, s2 = 0.f, s3 = 0.f;
            #pragma unroll
            for (int d = 0; d < LAT; d += 4) {
                s0 = fmaf(p[d + 0], ar[d + 0], s0);
                s1 = fmaf(p[d + 1], ar[d + 1], s1);
                s2 = fmaf(p[d + 2], ar[d + 2], s2);
                s3 = fmaf(p[d + 3], ar[d + 3], s3);
            }
            float d2 = pn + san[a] - 2.f * ((s0 + s1) + (s2 + s3));
            float w  = GRAV * __builtin_amdgcn_rcpf(d2);
            wsum += w;
            #pragma unroll
            for (int d = 0; d < LAT; ++d) F[d] = fmaf(w, ar[d], F[d]);
        }
        float npn = 0.f;
        const bool last = (it == NITER - 1);
        #pragma unroll
        for (int d = 0; d < LAT; ++d) {
            float delta = 0.1f * (F[d] - p[d] * wsum);
            if (last) cd = fmaf(delta, delta, cd);
            p[d] += delta;
            npn = fmaf(p[d], p[d], npn);
        }
        pn = npn;
    }

    // ---- reductions: field (sum over S per b) and global change ----
    const int b = blockIdx.x >> 3;   // 8 blocks of 256 tokens per batch row
    #pragma unroll
    for (int d = 0; d < LAT; ++d) {
        float v = p[d];
        #pragma unroll
        for (int off = 32; off > 0; off >>= 1) v += __shfl_down(v, off);
        if ((threadIdx.x & 63) == 0) atomicAdd(ws + WS_FIELD + b * LAT + d, v);
    }
    {
        float v = cd;
        #pragma unroll
        for (int off = 32; off > 0; off >>= 1) v += __shfl_down(v, off);
        if ((threadIdx.x & 63) == 0) atomicAdd(ws + WS_CHG, v);
    }
}

// ---------------------------------------------------------------------------
// Kernel 2: finalize field, decoder (rec -> ws), masses, change. One block.
// ---------------------------------------------------------------------------
__global__ __launch_bounds__(1024)
void k_finalize(const float* __restrict__ dw1, const float* __restrict__ db1,
                const float* __restrict__ dw2, const float* __restrict__ db2,
                const float* __restrict__ mw,  const float* __restrict__ mb,
                float* __restrict__ ws, float* __restrict__ out)
{
    __shared__ float sf[BB * LAT];
    __shared__ float sh[BB * HID];
    const int t = threadIdx.x;
    if (t < BB * LAT) {
        float f = ws[WS_FIELD + t] * (1.f / SS);
        sf[t] = f;
        out[OFF_FIELD + t] = f;
    }
    __syncthreads();
    if (t < BB * HID) {
        const int b = t >> 4, j = t & 15;
        float acc = db1[j];
        #pragma unroll
        for (int d = 0; d < LAT; ++d) acc = fmaf(sf[b * LAT + d], dw1[d * HID + j], acc);
        sh[t] = fmaxf(acc, 0.f);
    }
    if (t < BB) {
        float acc = mb[0];
        #pragma unroll
        for (int d = 0; d < LAT; ++d) acc = fmaf(sf[t * LAT + d], mw[d], acc);
        out[OFF_MASS + t] = 1.f / (1.f + expf(-acc));
    }
    if (t == 0) out[OFF_CHG] = sqrtf(ws[WS_CHG]);
    __syncthreads();
    for (int i = t; i < BB * IND; i += 1024) {
        const int b = i / IND, c = i - b * IND;
        float acc = db2[c];
        #pragma unroll
        for (int j = 0; j < HID; ++j) acc = fmaf(sh[b * HID + j], dw2[j * IND + c], acc);
        ws[WS_REC + i] = acc;
    }
}

// ---------------------------------------------------------------------------
// Kernel 3: broadcast rec[b][300] -> out[b][s][300]. 78.6 MB of float4 stores.
// 300 % 4 == 0 so every float4 store maps to an aligned float4 in the row.
// ---------------------------------------------------------------------------
#define CHUNK 8192                  // floats per block
#define CPB   (SS * IND / CHUNK)    // 75 chunks per batch row
__global__ __launch_bounds__(256)
void k_broadcast(const float* __restrict__ ws, float* __restrict__ out)
{
    __shared__ float srow[IND];
    const int b = blockIdx.x / CPB;
    const int c = blockIdx.x % CPB;
    if (threadIdx.x < IND / 4)
        ((float4*)srow)[threadIdx.x] =
            ((const float4*)(ws + WS_REC + b * IND))[threadIdx.x];
    __syncthreads();
    float4* o = (float4*)(out + OFF_REC + (size_t)b * (SS * IND) + (size_t)c * CHUNK);
    #pragma unroll
    for (int i = 0; i < CHUNK / 4 / 256; ++i) {
        const int o4 = i * 256 + threadIdx.x;
        const int g  = c * CHUNK + o4 * 4;  // flat float index within b-slab
        const int r  = g % IND;             // r % 4 == 0
        o[o4] = *(const float4*)(srow + r);
    }
}

extern "C" void kernel_launch(void* const* d_in, const int* in_sizes, int n_in,
                              void* d_out, int out_size, void* d_ws, size_t ws_size,
                              hipStream_t stream)
{
    const float* x   = (const float*)d_in[0];
    const float* ew1 = (const float*)d_in[1];
    const float* eb1 = (const float*)d_in[2];
    const float* ew2 = (const float*)d_in[3];
    const float* eb2 = (const float*)d_in[4];
    const float* att = (const float*)d_in[5];
    const float* dw1 = (const float*)d_in[6];
    const float* db1 = (const float*)d_in[7];
    const float* dw2 = (const float*)d_in[8];
    const float* db2 = (const float*)d_in[9];
    const float* mw  = (const float*)d_in[10];
    const float* mb  = (const float*)d_in[11];
    float* out = (float*)d_out;
    float* ws  = (float*)d_ws;

    hipMemsetAsync(ws, 0, (WS_CHG + 1) * sizeof(float), stream);
    k_enc_grav<<<BB * SS / 256, 256, 0, stream>>>(x, ew1, eb1, ew2, eb2, att, ws);
    k_finalize<<<1, 1024, 0, stream>>>(dw1, db1, dw2, db2, mw, mb, ws, out);
    k_broadcast<<<BB * CPB, 256, 0, stream>>>(ws, out);
}

// Round 3
// 286.282 us; speedup vs baseline: 1.0682x; 1.0682x over previous
//
#include <hip/hip_runtime.h>
#include <cmath>

#define BB 32
#define SS 2048
#define IND 300
#define HID 16
#define LAT 16
#define NA 64
#define NITER 20
#define GRAV 0.01f

// d_out layout (floats): field[32*16] | rec[32*2048*300] | masses[32] | change[1]
#define OFF_FIELD 0
#define OFF_REC   512
#define OFF_MASS  (512 + BB*SS*IND)
#define OFF_CHG   (OFF_MASS + BB)

// d_ws layout (floats)
#define WS_FIELD 0      // 512 accumulators
#define WS_CHG   512    // 1 accumulator
#define WS_REC   1024   // 9600 rec values

typedef __attribute__((ext_vector_type(8))) __bf16 bf16x8;
typedef __attribute__((ext_vector_type(4))) float f32x4;

#define PS   24   // P_lds row stride (bf16): 48B, 16B-aligned, 2-way-bank max
#define WST  72   // W_lds row stride (bf16): 144B, 16B-aligned, 2-way-bank max

// ---------------------------------------------------------------------------
// Fused encoder + MFMA gravity. Block = 256 threads = 4 waves = 64 tokens.
// Each wave owns 16 tokens. Gravity per iteration:
//   S[t][a] = P.A^T  (4x mfma_16x16x32_bf16, K zero-padded 16->32)
//   w = 1/d2 elementwise in C-layout, W -> LDS -> A-frag
//   F[t][d] = W.A    (2x mfma, K=64)
//   P update in C-layout fp32 (F C-frag aligns with P — no transpose).
// ---------------------------------------------------------------------------
__global__ __launch_bounds__(256, 4)
void k_enc_grav(const float* __restrict__ x, const float* __restrict__ w1,
                const float* __restrict__ b1, const float* __restrict__ w2,
                const float* __restrict__ b2, const float* __restrict__ att,
                float* __restrict__ ws)
{
    __shared__ float  hred[4][64][HID + 1];   // +1 pad: bank-conflict-free
    __shared__ __bf16 Pl[4][16 * PS];
    __shared__ __bf16 Wl[4][16 * WST];

    const int tid  = threadIdx.x;
    const int wave = tid >> 6, lane = tid & 63;
    const int quad = lane >> 4, col = lane & 15;
    const int tok0 = blockIdx.x * 64;

    // ---- encoder stage 1: partial h, 4 chunks of 75 inputs per token ----
    {
        const int tl = tid & 63;        // local token
        const int ck = tid >> 6;        // chunk (wave-uniform -> w1 s_loads)
        float h[HID];
        #pragma unroll
        for (int j = 0; j < HID; ++j) h[j] = 0.f;
        const float* xr = x + (size_t)(tok0 + tl) * IND + ck * 75;
        #pragma unroll 5
        for (int i = 0; i < 75; ++i) {
            float xv = xr[i];
            const float* wr = w1 + (ck * 75 + i) * HID;
            #pragma unroll
            for (int j = 0; j < HID; ++j) h[j] = fmaf(xv, wr[j], h[j]);
        }
        #pragma unroll
        for (int j = 0; j < HID; ++j) hred[ck][tl][j] = h[j];
    }
    __syncthreads();
    // ---- encoder stage 2: reduce chunks, +b1, relu ----
    {
        const int tl = tid & 63;
        const int jg = (tid >> 6) * 4;
        #pragma unroll
        for (int jj = 0; jj < 4; ++jj) {
            const int j = jg + jj;
            float s = hred[0][tl][j] + hred[1][tl][j] + hred[2][tl][j] + hred[3][tl][j];
            hred[0][tl][j] = fmaxf(s + b1[j], 0.f);
        }
    }
    __syncthreads();

    // ---- encoder stage 3: p in MFMA C-layout: p[r] = P[quad*4+r][col] ----
    float p[4];
    {
        float w2c[HID];
        #pragma unroll
        for (int j = 0; j < HID; ++j) w2c[j] = w2[j * LAT + col];
        const float bb2 = b2[col];
        #pragma unroll
        for (int r = 0; r < 4; ++r) {
            const int t = wave * 16 + quad * 4 + r;
            float acc = bb2;
            #pragma unroll
            for (int j = 0; j < HID; ++j) acc = fmaf(hred[0][t][j], w2c[j], acc);
            p[r] = acc;
        }
    }

    // ---- attractor fragments (constant over iterations) ----
    bf16x8 zero8;
    #pragma unroll
    for (int e = 0; e < 8; ++e) zero8[e] = (__bf16)0.f;
    const f32x4 zf = {0.f, 0.f, 0.f, 0.f};

    bf16x8 b1f[4], b2f[2];
    float sanv[4];
    #pragma unroll
    for (int i = 0; i < 4; ++i) {
        const float* arow = att + (16 * i + col) * LAT;
        float s = 0.f;
        #pragma unroll
        for (int k = 0; k < LAT; ++k) s = fmaf(arow[k], arow[k], s);
        sanv[i] = s;
        if (quad < 2) {
            #pragma unroll
            for (int j = 0; j < 8; ++j) b1f[i][j] = (__bf16)arow[quad * 8 + j];
        } else b1f[i] = zero8;
    }
    #pragma unroll
    for (int h = 0; h < 2; ++h)
        #pragma unroll
        for (int j = 0; j < 8; ++j)
            b2f[h][j] = (__bf16)att[(32 * h + quad * 8 + j) * LAT + col];

    __bf16* myP = Pl[wave];
    __bf16* myW = Wl[wave];
    #pragma unroll
    for (int r = 0; r < 4; ++r) myP[(quad * 4 + r) * PS + col] = (__bf16)p[r];

    float cd = 0.f;
    #pragma unroll 1
    for (int it = 0; it < NITER; ++it) {
        // pn[r] = |P[t_r]|^2 via 4-stage butterfly over the 16 cols
        float pn[4];
        #pragma unroll
        for (int r = 0; r < 4; ++r) {
            float s = p[r] * p[r];
            s += __shfl_xor(s, 1); s += __shfl_xor(s, 2);
            s += __shfl_xor(s, 4); s += __shfl_xor(s, 8);
            pn[r] = s;
        }
        // A-frag of P: A[m=col][k=quad*8+j], k>=16 is zero
        bf16x8 ap = zero8;
        if (quad < 2) ap = *(bf16x8*)(myP + col * PS + quad * 8);

        f32x4 sf[4];
        #pragma unroll
        for (int i = 0; i < 4; ++i)
            sf[i] = __builtin_amdgcn_mfma_f32_16x16x32_bf16(ap, b1f[i], zf, 0, 0, 0);

        // w = 1/d2 (GRAV folded into the update), wsum per token row
        float wsum[4] = {0.f, 0.f, 0.f, 0.f};
        #pragma unroll
        for (int i = 0; i < 4; ++i) {
            #pragma unroll
            for (int r = 0; r < 4; ++r) {
                float d2 = fmaf(sf[i][r], -2.f, pn[r] + sanv[i]);
                float w  = __builtin_amdgcn_rcpf(d2);
                wsum[r] += w;
                myW[(quad * 4 + r) * WST + 16 * i + col] = (__bf16)w;
            }
        }
        #pragma unroll
        for (int r = 0; r < 4; ++r) {
            float s = wsum[r];
            s += __shfl_xor(s, 1); s += __shfl_xor(s, 2);
            s += __shfl_xor(s, 4); s += __shfl_xor(s, 8);
            wsum[r] = s;
        }
        // W A-frags: A[m=col][k=quad*8+j (+32)]
        bf16x8 wa0 = *(bf16x8*)(myW + col * WST + quad * 8);
        bf16x8 wa1 = *(bf16x8*)(myW + col * WST + 32 + quad * 8);
        f32x4 F = __builtin_amdgcn_mfma_f32_16x16x32_bf16(wa0, b2f[0], zf, 0, 0, 0);
        F = __builtin_amdgcn_mfma_f32_16x16x32_bf16(wa1, b2f[1], F, 0, 0, 0);

        // update: p += 0.1*G*(F - p*wsum)
        const bool last = (it == NITER - 1);
        #pragma unroll
        for (int r = 0; r < 4; ++r) {
            float c  = fmaf(wsum[r], -0.1f * GRAV, 1.0f);
            float np = fmaf(p[r], c, (0.1f * GRAV) * F[r]);
            if (last) { float d = np - p[r]; cd = fmaf(d, d, cd); }
            p[r] = np;
            myP[(quad * 4 + r) * PS + col] = (__bf16)np;
        }
    }

    // ---- reductions ----
    float fs = (p[0] + p[1]) + (p[2] + p[3]);
    fs += __shfl_xor(fs, 16); fs += __shfl_xor(fs, 32);
    const int b = blockIdx.x >> 5;   // 32 blocks (64 tokens) per batch row
    if (lane < 16) atomicAdd(ws + WS_FIELD + b * LAT + lane, fs);

    float c2 = cd;
    c2 += __shfl_xor(c2, 1);  c2 += __shfl_xor(c2, 2);  c2 += __shfl_xor(c2, 4);
    c2 += __shfl_xor(c2, 8);  c2 += __shfl_xor(c2, 16); c2 += __shfl_xor(c2, 32);
    if (lane == 0) atomicAdd(ws + WS_CHG, c2);
}

// ---------------------------------------------------------------------------
// Kernel 2: finalize — one block per batch row (32 blocks).
// ---------------------------------------------------------------------------
__global__ __launch_bounds__(512)
void k_finalize(const float* __restrict__ dw1, const float* __restrict__ db1,
                const float* __restrict__ dw2, const float* __restrict__ db2,
                const float* __restrict__ mw,  const float* __restrict__ mb,
                float* __restrict__ ws, float* __restrict__ out)
{
    __shared__ float sf[LAT];
    __shared__ float sh[HID];
    const int b = blockIdx.x, t = threadIdx.x;
    if (t < LAT) {
        float f = ws[WS_FIELD + b * LAT + t] * (1.f / SS);
        sf[t] = f;
        out[OFF_FIELD + b * LAT + t] = f;
    }
    __syncthreads();
    if (t < HID) {
        float a = db1[t];
        #pragma unroll
        for (int d = 0; d < LAT; ++d) a = fmaf(sf[d], dw1[d * HID + t], a);
        sh[t] = fmaxf(a, 0.f);
    }
    if (t == 32) {
        float a = mb[0];
        #pragma unroll
        for (int d = 0; d < LAT; ++d) a = fmaf(sf[d], mw[d], a);
        out[OFF_MASS + b] = 1.f / (1.f + expf(-a));
    }
    if (b == 0 && t == 33) out[OFF_CHG] = sqrtf(ws[WS_CHG]);
    __syncthreads();
    if (t < IND) {
        float a = db2[t];
        #pragma unroll
        for (int j = 0; j < HID; ++j) a = fmaf(sh[j], dw2[j * IND + t], a);
        ws[WS_REC + b * IND + t] = a;
    }
}

// ---------------------------------------------------------------------------
// Kernel 3: broadcast rec[b][300] -> out[b][s][300]; row from L1/L2, NT stores.
// Uses clang ext-vector f32x4 (HIP float4 is a class type the NT builtin rejects).
// ---------------------------------------------------------------------------
#define CHUNK 8192
#define CPB   (SS * IND / CHUNK)    // 75
__global__ __launch_bounds__(256)
void k_broadcast(const float* __restrict__ ws, float* __restrict__ out)
{
    const int b = blockIdx.x / CPB;
    const int c = blockIdx.x % CPB;
    const float* row = ws + WS_REC + b * IND;
    f32x4* o = (f32x4*)(out + OFF_REC + (size_t)b * (SS * IND) + (size_t)c * CHUNK);
    #pragma unroll
    for (int i = 0; i < CHUNK / 4 / 256; ++i) {
        const int o4 = i * 256 + threadIdx.x;
        const int r  = (c * CHUNK + o4 * 4) % IND;   // r % 4 == 0
        f32x4 v = *(const f32x4*)(row + r);
        __builtin_nontemporal_store(v, o + o4);
    }
}

extern "C" void kernel_launch(void* const* d_in, const int* in_sizes, int n_in,
                              void* d_out, int out_size, void* d_ws, size_t ws_size,
                              hipStream_t stream)
{
    const float* x   = (const float*)d_in[0];
    const float* ew1 = (const float*)d_in[1];
    const float* eb1 = (const float*)d_in[2];
    const float* ew2 = (const float*)d_in[3];
    const float* eb2 = (const float*)d_in[4];
    const float* att = (const float*)d_in[5];
    const float* dw1 = (const float*)d_in[6];
    const float* db1 = (const float*)d_in[7];
    const float* dw2 = (const float*)d_in[8];
    const float* db2 = (const float*)d_in[9];
    const float* mw  = (const float*)d_in[10];
    const float* mb  = (const float*)d_in[11];
    float* out = (float*)d_out;
    float* ws  = (float*)d_ws;

    (void)hipMemsetAsync(ws, 0, (WS_CHG + 1) * sizeof(float), stream);
    k_enc_grav<<<BB * SS / 64, 256, 0, stream>>>(x, ew1, eb1, ew2, eb2, att, ws);
    k_finalize<<<BB, 512, 0, stream>>>(dw1, db1, dw2, db2, mw, mb, ws, out);
    k_broadcast<<<BB * CPB, 256, 0, stream>>>(ws, out);
}

// Round 4
// 272.734 us; speedup vs baseline: 1.1213x; 1.0497x over previous
//
#include <hip/hip_runtime.h>
#include <cmath>

#define BB 32
#define SS 2048
#define IND 300
#define HID 16
#define LAT 16
#define NA 64
#define NITER 20
#define GRAV 0.01f

// d_out layout (floats): field[32*16] | rec[32*2048*300] | masses[32] | change[1]
#define OFF_FIELD 0
#define OFF_REC   512
#define OFF_MASS  (512 + BB*SS*IND)
#define OFF_CHG   (OFF_MASS + BB)

// d_ws layout (floats)
#define WS_FIELD 0      // 512 accumulators
#define WS_CHG   512    // 1 accumulator
#define WS_REC   1024   // 9600 rec values

typedef __attribute__((ext_vector_type(8))) __bf16 bf16x8;
typedef __attribute__((ext_vector_type(4))) float f32x4;

#define PS   24   // P_lds row stride (bf16): 48B, 16B-aligned
#define WST  72   // W_lds row stride (bf16): 144B, 16B-aligned

// ---------------------------------------------------------------------------
// Fused encoder + MFMA gravity. Block = 256 threads = 4 waves = 64 tokens.
// LDS phases alias: encoder hred[4][64][17] (17.4 KB) then Pl+Wl (12.3 KB).
// launch_bounds(256,1): do NOT cap the unified VGPR/AGPR budget — R3's
// (256,4) cap caused 68 MB of scratch spill traffic (the 155 us stall).
// ---------------------------------------------------------------------------
__global__ __launch_bounds__(256, 1)
void k_enc_grav(const float* __restrict__ x, const float* __restrict__ w1,
                const float* __restrict__ b1, const float* __restrict__ w2,
                const float* __restrict__ b2, const float* __restrict__ att,
                float* __restrict__ ws)
{
    __shared__ __align__(16) char smem[4 * 64 * (HID + 1) * 4];   // 17408 B
    float  (*hred)[64][HID + 1] = (float(*)[64][HID + 1])smem;
    __bf16* Pl = (__bf16*)smem;            // 4 waves * 16*PS  = 3072 B
    __bf16* Wl = (__bf16*)(smem + 3072);   // 4 waves * 16*WST = 9216 B

    const int tid  = threadIdx.x;
    const int wave = tid >> 6, lane = tid & 63;
    const int quad = lane >> 4, col = lane & 15;
    const int tok0 = blockIdx.x * 64;

    // ---- encoder stage 1: partial h; chunks 76/76/76/72 (16B-aligned) ----
    {
        const int tl = tid & 63;        // local token
        const int ck = tid >> 6;        // chunk id (wave-uniform -> w1 s_load)
        const int base = ck * 76;
        const float* xrow = x + (size_t)(tok0 + tl) * IND + base;
        float h[HID];
        #pragma unroll
        for (int j = 0; j < HID; ++j) h[j] = 0.f;
        #pragma unroll 6
        for (int i = 0; i < 18; ++i) {
            f32x4 xv = *(const f32x4*)(xrow + i * 4);
            const float* wr = w1 + (base + i * 4) * HID;
            #pragma unroll
            for (int c = 0; c < 4; ++c)
                #pragma unroll
                for (int j = 0; j < HID; ++j)
                    h[j] = fmaf(xv[c], wr[c * HID + j], h[j]);
        }
        if (ck < 3) {                   // wave-uniform branch: 19th float4
            f32x4 xv = *(const f32x4*)(xrow + 72);
            const float* wr = w1 + (base + 72) * HID;
            #pragma unroll
            for (int c = 0; c < 4; ++c)
                #pragma unroll
                for (int j = 0; j < HID; ++j)
                    h[j] = fmaf(xv[c], wr[c * HID + j], h[j]);
        }
        #pragma unroll
        for (int j = 0; j < HID; ++j) hred[ck][tl][j] = h[j];
    }
    __syncthreads();
    // ---- encoder stage 2: reduce chunks, +b1, relu ----
    {
        const int tl = tid & 63;
        const int jg = (tid >> 6) * 4;
        #pragma unroll
        for (int jj = 0; jj < 4; ++jj) {
            const int j = jg + jj;
            float s = (hred[0][tl][j] + hred[1][tl][j]) +
                      (hred[2][tl][j] + hred[3][tl][j]);
            hred[0][tl][j] = fmaxf(s + b1[j], 0.f);
        }
    }
    __syncthreads();

    // ---- encoder stage 3: p in MFMA C-layout: p[r] = P[quad*4+r][col] ----
    float p[4];
    {
        float w2c[HID];
        #pragma unroll
        for (int j = 0; j < HID; ++j) w2c[j] = w2[j * LAT + col];
        const float bb2 = b2[col];
        #pragma unroll
        for (int r = 0; r < 4; ++r) {
            const int t = wave * 16 + quad * 4 + r;
            float acc = bb2;
            #pragma unroll
            for (int j = 0; j < HID; ++j) acc = fmaf(hred[0][t][j], w2c[j], acc);
            p[r] = acc;
        }
    }
    __syncthreads();   // hred dead; Pl/Wl may now overwrite it

    // ---- attractor fragments (constant over iterations) ----
    bf16x8 zero8;
    #pragma unroll
    for (int e = 0; e < 8; ++e) zero8[e] = (__bf16)0.f;
    const f32x4 zf = {0.f, 0.f, 0.f, 0.f};

    bf16x8 b1f[4], b2f[2];
    float sanv[4];
    #pragma unroll
    for (int i = 0; i < 4; ++i) {
        const float* arow = att + (16 * i + col) * LAT;
        float s = 0.f;
        #pragma unroll
        for (int k = 0; k < LAT; ++k) s = fmaf(arow[k], arow[k], s);
        sanv[i] = s;
        if (quad < 2) {
            #pragma unroll
            for (int j = 0; j < 8; ++j) b1f[i][j] = (__bf16)arow[quad * 8 + j];
        } else b1f[i] = zero8;
    }
    #pragma unroll
    for (int h = 0; h < 2; ++h)
        #pragma unroll
        for (int j = 0; j < 8; ++j)
            b2f[h][j] = (__bf16)att[(32 * h + quad * 8 + j) * LAT + col];

    __bf16* myP = Pl + wave * 16 * PS;
    __bf16* myW = Wl + wave * 16 * WST;
    #pragma unroll
    for (int r = 0; r < 4; ++r) myP[(quad * 4 + r) * PS + col] = (__bf16)p[r];

    float cd = 0.f;
    #pragma unroll 1
    for (int it = 0; it < NITER; ++it) {
        // pn[r] = |P[t_r]|^2 via 4-stage butterfly over the 16 cols
        float pn[4];
        #pragma unroll
        for (int r = 0; r < 4; ++r) {
            float s = p[r] * p[r];
            s += __shfl_xor(s, 1); s += __shfl_xor(s, 2);
            s += __shfl_xor(s, 4); s += __shfl_xor(s, 8);
            pn[r] = s;
        }
        // A-frag of P: A[m=col][k=quad*8+j], k>=16 is zero
        bf16x8 ap = zero8;
        if (quad < 2) ap = *(bf16x8*)(myP + col * PS + quad * 8);

        f32x4 sf[4];
        #pragma unroll
        for (int i = 0; i < 4; ++i)
            sf[i] = __builtin_amdgcn_mfma_f32_16x16x32_bf16(ap, b1f[i], zf, 0, 0, 0);

        // w = 1/d2 (GRAV folded into the update), wsum per token row
        float wsum[4] = {0.f, 0.f, 0.f, 0.f};
        #pragma unroll
        for (int i = 0; i < 4; ++i) {
            #pragma unroll
            for (int r = 0; r < 4; ++r) {
                float d2 = fmaf(sf[i][r], -2.f, pn[r] + sanv[i]);
                float w  = __builtin_amdgcn_rcpf(d2);
                wsum[r] += w;
                myW[(quad * 4 + r) * WST + 16 * i + col] = (__bf16)w;
            }
        }
        #pragma unroll
        for (int r = 0; r < 4; ++r) {
            float s = wsum[r];
            s += __shfl_xor(s, 1); s += __shfl_xor(s, 2);
            s += __shfl_xor(s, 4); s += __shfl_xor(s, 8);
            wsum[r] = s;
        }
        // W A-frags: A[m=col][k=quad*8+j (+32)]
        bf16x8 wa0 = *(bf16x8*)(myW + col * WST + quad * 8);
        bf16x8 wa1 = *(bf16x8*)(myW + col * WST + 32 + quad * 8);
        f32x4 F = __builtin_amdgcn_mfma_f32_16x16x32_bf16(wa0, b2f[0], zf, 0, 0, 0);
        F = __builtin_amdgcn_mfma_f32_16x16x32_bf16(wa1, b2f[1], F, 0, 0, 0);

        // update: p += 0.1*G*(F - p*wsum)
        const bool last = (it == NITER - 1);
        #pragma unroll
        for (int r = 0; r < 4; ++r) {
            float c  = fmaf(wsum[r], -0.1f * GRAV, 1.0f);
            float np = fmaf(p[r], c, (0.1f * GRAV) * F[r]);
            if (last) { float d = np - p[r]; cd = fmaf(d, d, cd); }
            p[r] = np;
            myP[(quad * 4 + r) * PS + col] = (__bf16)np;
        }
    }

    // ---- reductions ----
    float fs = (p[0] + p[1]) + (p[2] + p[3]);
    fs += __shfl_xor(fs, 16); fs += __shfl_xor(fs, 32);
    const int b = blockIdx.x >> 5;   // 32 blocks (64 tokens) per batch row
    if (lane < 16) atomicAdd(ws + WS_FIELD + b * LAT + lane, fs);

    float c2 = cd;
    c2 += __shfl_xor(c2, 1);  c2 += __shfl_xor(c2, 2);  c2 += __shfl_xor(c2, 4);
    c2 += __shfl_xor(c2, 8);  c2 += __shfl_xor(c2, 16); c2 += __shfl_xor(c2, 32);
    if (lane == 0) atomicAdd(ws + WS_CHG, c2);
}

// ---------------------------------------------------------------------------
// Kernel 2: finalize — one block per batch row (32 blocks).
// ---------------------------------------------------------------------------
__global__ __launch_bounds__(512)
void k_finalize(const float* __restrict__ dw1, const float* __restrict__ db1,
                const float* __restrict__ dw2, const float* __restrict__ db2,
                const float* __restrict__ mw,  const float* __restrict__ mb,
                float* __restrict__ ws, float* __restrict__ out)
{
    __shared__ float sf[LAT];
    __shared__ float sh[HID];
    const int b = blockIdx.x, t = threadIdx.x;
    if (t < LAT) {
        float f = ws[WS_FIELD + b * LAT + t] * (1.f / SS);
        sf[t] = f;
        out[OFF_FIELD + b * LAT + t] = f;
    }
    __syncthreads();
    if (t < HID) {
        float a = db1[t];
        #pragma unroll
        for (int d = 0; d < LAT; ++d) a = fmaf(sf[d], dw1[d * HID + t], a);
        sh[t] = fmaxf(a, 0.f);
    }
    if (t == 32) {
        float a = mb[0];
        #pragma unroll
        for (int d = 0; d < LAT; ++d) a = fmaf(sf[d], mw[d], a);
        out[OFF_MASS + b] = 1.f / (1.f + expf(-a));
    }
    if (b == 0 && t == 33) out[OFF_CHG] = sqrtf(ws[WS_CHG]);
    __syncthreads();
    if (t < IND) {
        float a = db2[t];
        #pragma unroll
        for (int j = 0; j < HID; ++j) a = fmaf(sh[j], dw2[j * IND + t], a);
        ws[WS_REC + b * IND + t] = a;
    }
}

// ---------------------------------------------------------------------------
// Kernel 3: broadcast rec[b][300] -> out[b][s][300]; row from L1/L2, NT stores.
// ---------------------------------------------------------------------------
#define CHUNK 8192
#define CPB   (SS * IND / CHUNK)    // 75
__global__ __launch_bounds__(256)
void k_broadcast(const float* __restrict__ ws, float* __restrict__ out)
{
    const int b = blockIdx.x / CPB;
    const int c = blockIdx.x % CPB;
    const float* row = ws + WS_REC + b * IND;
    f32x4* o = (f32x4*)(out + OFF_REC + (size_t)b * (SS * IND) + (size_t)c * CHUNK);
    #pragma unroll
    for (int i = 0; i < CHUNK / 4 / 256; ++i) {
        const int o4 = i * 256 + threadIdx.x;
        const int r  = (c * CHUNK + o4 * 4) % IND;   // r % 4 == 0
        f32x4 v = *(const f32x4*)(row + r);
        __builtin_nontemporal_store(v, o + o4);
    }
}

extern "C" void kernel_launch(void* const* d_in, const int* in_sizes, int n_in,
                              void* d_out, int out_size, void* d_ws, size_t ws_size,
                              hipStream_t stream)
{
    const float* x   = (const float*)d_in[0];
    const float* ew1 = (const float*)d_in[1];
    const float* eb1 = (const float*)d_in[2];
    const float* ew2 = (const float*)d_in[3];
    const float* eb2 = (const float*)d_in[4];
    const float* att = (const float*)d_in[5];
    const float* dw1 = (const float*)d_in[6];
    const float* db1 = (const float*)d_in[7];
    const float* dw2 = (const float*)d_in[8];
    const float* db2 = (const float*)d_in[9];
    const float* mw  = (const float*)d_in[10];
    const float* mb  = (const float*)d_in[11];
    float* out = (float*)d_out;
    float* ws  = (float*)d_ws;

    (void)hipMemsetAsync(ws, 0, (WS_CHG + 1) * sizeof(float), stream);
    k_enc_grav<<<BB * SS / 64, 256, 0, stream>>>(x, ew1, eb1, ew2, eb2, att, ws);
    k_finalize<<<BB, 512, 0, stream>>>(dw1, db1, dw2, db2, mw, mb, ws, out);
    k_broadcast<<<BB * CPB, 256, 0, stream>>>(ws, out);
}

// Round 5
// 239.061 us; speedup vs baseline: 1.2793x; 1.1409x over previous
//
#include <hip/hip_runtime.h>
#include <cmath>

#define BB 32
#define SS 2048
#define IND 300
#define HID 16
#define LAT 16
#define NA 64
#define NITER 20
#define GRAV 0.01f

// d_out layout (floats): field[32*16] | rec[32*2048*300] | masses[32] | change[1]
#define OFF_FIELD 0
#define OFF_REC   512
#define OFF_MASS  (512 + BB*SS*IND)
#define OFF_CHG   (OFF_MASS + BB)

// d_ws layout (floats)
#define WS_FIELD 0      // 512 accumulators
#define WS_CHG   512    // 1 accumulator
#define WS_REC   1024   // 9600 rec values

typedef __attribute__((ext_vector_type(8))) __bf16 bf16x8;
typedef __attribute__((ext_vector_type(4))) __bf16 bf16x4;
typedef __attribute__((ext_vector_type(2))) __bf16 bf16x2;
typedef __attribute__((ext_vector_type(4))) float f32x4;

#define PS2  40   // augmented P row stride (bf16): 80 B; b128 reads 16B-aligned, 2-way banks
#define WST  72   // W row stride (bf16): 144 B; b128 reads 16B-aligned, 2-way banks

// ---------------------------------------------------------------------------
// Fused encoder + MFMA gravity, butterfly-free.
// Per iteration: S_aug = P_aug . B1  (A: k-interleaved (p, p^2); B1: (-2a, 1))
//   -> d2 = S_aug + |a|^2 directly (pn folded into MFMA — no shfl butterfly)
// w = rcp(d2); wsum via F2 = W . ones MFMA (no second butterfly).
// P round-trip: 4x ds_write_b32 + 1x ds_read_b128. W: 4x b64 + 2x b128
// (attractor order permuted so each lane's 4 w's pack into one b64; the
// B2 fragment uses the same permutation).
// launch_bounds(256,1): no VGPR cap — (256,4) caused 68 MB spill in R3.
// ---------------------------------------------------------------------------
__global__ __launch_bounds__(256, 1)
void k_enc_grav(const float* __restrict__ x, const float* __restrict__ w1,
                const float* __restrict__ b1, const float* __restrict__ w2,
                const float* __restrict__ b2, const float* __restrict__ att,
                float* __restrict__ ws)
{
    __shared__ __align__(16) char smem[4 * 64 * (HID + 1) * 4];   // 17408 B
    float  (*hred)[64][HID + 1] = (float(*)[64][HID + 1])smem;
    __bf16* Pl = (__bf16*)smem;            // 4 waves * 16*PS2*2B = 5120 B
    __bf16* Wl = (__bf16*)(smem + 5120);   // 4 waves * 16*WST*2B = 9216 B

    const int tid  = threadIdx.x;
    const int wave = tid >> 6, lane = tid & 63;
    const int quad = lane >> 4, col = lane & 15;
    const int tok0 = blockIdx.x * 64;

    // ---- encoder stage 1: partial h; chunks 76/76/76/72 (16B-aligned) ----
    {
        const int tl = tid & 63;        // local token
        const int ck = tid >> 6;        // chunk id (wave-uniform -> w1 s_load)
        const int base = ck * 76;
        const float* xrow = x + (size_t)(tok0 + tl) * IND + base;
        float h[HID];
        #pragma unroll
        for (int j = 0; j < HID; ++j) h[j] = 0.f;
        #pragma unroll 6
        for (int i = 0; i < 18; ++i) {
            f32x4 xv = *(const f32x4*)(xrow + i * 4);
            const float* wr = w1 + (base + i * 4) * HID;
            #pragma unroll
            for (int c = 0; c < 4; ++c)
                #pragma unroll
                for (int j = 0; j < HID; ++j)
                    h[j] = fmaf(xv[c], wr[c * HID + j], h[j]);
        }
        if (ck < 3) {                   // wave-uniform branch: 19th float4
            f32x4 xv = *(const f32x4*)(xrow + 72);
            const float* wr = w1 + (base + 72) * HID;
            #pragma unroll
            for (int c = 0; c < 4; ++c)
                #pragma unroll
                for (int j = 0; j < HID; ++j)
                    h[j] = fmaf(xv[c], wr[c * HID + j], h[j]);
        }
        #pragma unroll
        for (int j = 0; j < HID; ++j) hred[ck][tl][j] = h[j];
    }
    __syncthreads();
    // ---- encoder stage 2: reduce chunks, +b1, relu ----
    {
        const int tl = tid & 63;
        const int jg = (tid >> 6) * 4;
        #pragma unroll
        for (int jj = 0; jj < 4; ++jj) {
            const int j = jg + jj;
            float s = (hred[0][tl][j] + hred[1][tl][j]) +
                      (hred[2][tl][j] + hred[3][tl][j]);
            hred[0][tl][j] = fmaxf(s + b1[j], 0.f);
        }
    }
    __syncthreads();

    // ---- encoder stage 3: p in MFMA C-layout: p[r] = P[quad*4+r][col] ----
    float p[4];
    {
        float w2c[HID];
        #pragma unroll
        for (int j = 0; j < HID; ++j) w2c[j] = w2[j * LAT + col];
        const float bb2 = b2[col];
        #pragma unroll
        for (int r = 0; r < 4; ++r) {
            const int t = wave * 16 + quad * 4 + r;
            float acc = bb2;
            #pragma unroll
            for (int j = 0; j < HID; ++j) acc = fmaf(hred[0][t][j], w2c[j], acc);
            p[r] = acc;
        }
    }
    __syncthreads();   // hred dead; Pl/Wl may now overwrite it

    // ---- constant fragments ----
    const f32x4 zf = {0.f, 0.f, 0.f, 0.f};
    bf16x8 ones8;
    #pragma unroll
    for (int e = 0; e < 8; ++e) ones8[e] = (__bf16)1.0f;

    // B1 aug: B[k][a=16i+col]: k even -> -2*att[a][k/2], k odd -> 1
    bf16x8 b1aug[4];
    float sanv[4];
    #pragma unroll
    for (int i = 0; i < 4; ++i) {
        const float* arow = att + (16 * i + col) * LAT;
        float s = 0.f;
        #pragma unroll
        for (int k = 0; k < LAT; ++k) s = fmaf(arow[k], arow[k], s);
        sanv[i] = s;
        #pragma unroll
        for (int j = 0; j < 8; ++j) {
            const int k = quad * 8 + j;
            b1aug[i][j] = (k & 1) ? (__bf16)1.0f : (__bf16)(-2.0f * arow[k >> 1]);
        }
    }
    // B2 (F = W.A2) with permuted a-order: pos k -> a = (k&3)*16 + (k>>2)
    bf16x8 b2f[2];
    #pragma unroll
    for (int h = 0; h < 2; ++h)
        #pragma unroll
        for (int j = 0; j < 8; ++j) {
            const int k = 32 * h + quad * 8 + j;
            const int a = (k & 3) * 16 + (k >> 2);
            b2f[h][j] = (__bf16)att[a * LAT + col];
        }

    __bf16* myP = Pl + wave * 16 * PS2;
    __bf16* myW = Wl + wave * 16 * WST;

    float cd = 0.f;
    #pragma unroll 1
    for (int it = 0; it < NITER; ++it) {
        // pack (p, p^2) interleaved into row t=quad*4+r at k=2*col
        #pragma unroll
        for (int r = 0; r < 4; ++r) {
            bf16x2 pk = { (__bf16)p[r], (__bf16)(p[r] * p[r]) };
            *(bf16x2*)(myP + (quad * 4 + r) * PS2 + 2 * col) = pk;
        }
        bf16x8 ap = *(bf16x8*)(myP + col * PS2 + quad * 8);

        f32x4 sf[4];
        #pragma unroll
        for (int i = 0; i < 4; ++i)
            sf[i] = __builtin_amdgcn_mfma_f32_16x16x32_bf16(ap, b1aug[i], zf, 0, 0, 0);

        // w = 1/d2; d2 = (pn - 2 p.a) + |a|^2  (pn came out of the MFMA)
        float w_[4][4];
        #pragma unroll
        for (int i = 0; i < 4; ++i)
            #pragma unroll
            for (int r = 0; r < 4; ++r)
                w_[i][r] = __builtin_amdgcn_rcpf(sf[i][r] + sanv[i]);
        // pack 4 w's (a = col, 16+col, 32+col, 48+col -> adjacent in perm order)
        #pragma unroll
        for (int r = 0; r < 4; ++r) {
            bf16x4 wp = { (__bf16)w_[0][r], (__bf16)w_[1][r],
                          (__bf16)w_[2][r], (__bf16)w_[3][r] };
            *(bf16x4*)(myW + (quad * 4 + r) * WST + 4 * col) = wp;
        }
        bf16x8 wa0 = *(bf16x8*)(myW + col * WST + quad * 8);
        bf16x8 wa1 = *(bf16x8*)(myW + col * WST + 32 + quad * 8);

        f32x4 F = __builtin_amdgcn_mfma_f32_16x16x32_bf16(wa0, b2f[0], zf, 0, 0, 0);
        F  = __builtin_amdgcn_mfma_f32_16x16x32_bf16(wa1, b2f[1], F, 0, 0, 0);
        f32x4 F2 = __builtin_amdgcn_mfma_f32_16x16x32_bf16(wa0, ones8, zf, 0, 0, 0);
        F2 = __builtin_amdgcn_mfma_f32_16x16x32_bf16(wa1, ones8, F2, 0, 0, 0);

        // update: p = p*(1 - 0.1*G*wsum) + 0.1*G*F
        const bool last = (it == NITER - 1);
        #pragma unroll
        for (int r = 0; r < 4; ++r) {
            float np = fmaf(p[r], fmaf(F2[r], -0.1f * GRAV, 1.0f),
                            (0.1f * GRAV) * F[r]);
            if (last) { float d = np - p[r]; cd = fmaf(d, d, cd); }
            p[r] = np;
        }
    }

    // ---- reductions ----
    float fs = (p[0] + p[1]) + (p[2] + p[3]);
    fs += __shfl_xor(fs, 16); fs += __shfl_xor(fs, 32);
    const int b = blockIdx.x >> 5;   // 32 blocks (64 tokens) per batch row
    if (lane < 16) atomicAdd(ws + WS_FIELD + b * LAT + lane, fs);

    float c2 = cd;
    c2 += __shfl_xor(c2, 1);  c2 += __shfl_xor(c2, 2);  c2 += __shfl_xor(c2, 4);
    c2 += __shfl_xor(c2, 8);  c2 += __shfl_xor(c2, 16); c2 += __shfl_xor(c2, 32);
    if (lane == 0) atomicAdd(ws + WS_CHG, c2);
}

// ---------------------------------------------------------------------------
// Kernel 2: finalize — one block per batch row (32 blocks).
// ---------------------------------------------------------------------------
__global__ __launch_bounds__(512)
void k_finalize(const float* __restrict__ dw1, const float* __restrict__ db1,
                const float* __restrict__ dw2, const float* __restrict__ db2,
                const float* __restrict__ mw,  const float* __restrict__ mb,
                float* __restrict__ ws, float* __restrict__ out)
{
    __shared__ float sf[LAT];
    __shared__ float sh[HID];
    const int b = blockIdx.x, t = threadIdx.x;
    if (t < LAT) {
        float f = ws[WS_FIELD + b * LAT + t] * (1.f / SS);
        sf[t] = f;
        out[OFF_FIELD + b * LAT + t] = f;
    }
    __syncthreads();
    if (t < HID) {
        float a = db1[t];
        #pragma unroll
        for (int d = 0; d < LAT; ++d) a = fmaf(sf[d], dw1[d * HID + t], a);
        sh[t] = fmaxf(a, 0.f);
    }
    if (t == 32) {
        float a = mb[0];
        #pragma unroll
        for (int d = 0; d < LAT; ++d) a = fmaf(sf[d], mw[d], a);
        out[OFF_MASS + b] = 1.f / (1.f + expf(-a));
    }
    if (b == 0 && t == 33) out[OFF_CHG] = sqrtf(ws[WS_CHG]);
    __syncthreads();
    if (t < IND) {
        float a = db2[t];
        #pragma unroll
        for (int j = 0; j < HID; ++j) a = fmaf(sh[j], dw2[j * IND + t], a);
        ws[WS_REC + b * IND + t] = a;
    }
}

// ---------------------------------------------------------------------------
// Kernel 3: broadcast rec[b][300] -> out[b][s][300]; row from L1/L2, NT stores.
// ---------------------------------------------------------------------------
#define CHUNK 8192
#define CPB   (SS * IND / CHUNK)    // 75
__global__ __launch_bounds__(256)
void k_broadcast(const float* __restrict__ ws, float* __restrict__ out)
{
    const int b = blockIdx.x / CPB;
    const int c = blockIdx.x % CPB;
    const float* row = ws + WS_REC + b * IND;
    f32x4* o = (f32x4*)(out + OFF_REC + (size_t)b * (SS * IND) + (size_t)c * CHUNK);
    #pragma unroll
    for (int i = 0; i < CHUNK / 4 / 256; ++i) {
        const int o4 = i * 256 + threadIdx.x;
        const int r  = (c * CHUNK + o4 * 4) % IND;   // r % 4 == 0
        f32x4 v = *(const f32x4*)(row + r);
        __builtin_nontemporal_store(v, o + o4);
    }
}

extern "C" void kernel_launch(void* const* d_in, const int* in_sizes, int n_in,
                              void* d_out, int out_size, void* d_ws, size_t ws_size,
                              hipStream_t stream)
{
    const float* x   = (const float*)d_in[0];
    const float* ew1 = (const float*)d_in[1];
    const float* eb1 = (const float*)d_in[2];
    const float* ew2 = (const float*)d_in[3];
    const float* eb2 = (const float*)d_in[4];
    const float* att = (const float*)d_in[5];
    const float* dw1 = (const float*)d_in[6];
    const float* db1 = (const float*)d_in[7];
    const float* dw2 = (const float*)d_in[8];
    const float* db2 = (const float*)d_in[9];
    const float* mw  = (const float*)d_in[10];
    const float* mb  = (const float*)d_in[11];
    float* out = (float*)d_out;
    float* ws  = (float*)d_ws;

    (void)hipMemsetAsync(ws, 0, (WS_CHG + 1) * sizeof(float), stream);
    k_enc_grav<<<BB * SS / 64, 256, 0, stream>>>(x, ew1, eb1, ew2, eb2, att, ws);
    k_finalize<<<BB, 512, 0, stream>>>(dw1, db1, dw2, db2, mw, mb, ws, out);
    k_broadcast<<<BB * CPB, 256, 0, stream>>>(ws, out);
}

// Round 6
// 237.565 us; speedup vs baseline: 1.2873x; 1.0063x over previous
//
#include <hip/hip_runtime.h>
#include <cmath>

#define BB 32
#define SS 2048
#define IND 300
#define HID 16
#define LAT 16
#define NA 64
#define NITER 20
#define GRAV 0.01f

// d_out layout (floats): field[32*16] | rec[32*2048*300] | masses[32] | change[1]
#define OFF_FIELD 0
#define OFF_REC   512
#define OFF_MASS  (512 + BB*SS*IND)
#define OFF_CHG   (OFF_MASS + BB)

// d_ws layout (floats)
#define WS_FIELD 0      // 512 accumulators
#define WS_CHG   512    // 1 accumulator
#define WS_REC   1024   // 9600 rec values

typedef __attribute__((ext_vector_type(8))) __bf16 bf16x8;
typedef __attribute__((ext_vector_type(4))) __bf16 bf16x4;
typedef __attribute__((ext_vector_type(4))) float f32x4;

#define WTS 80   // W_lds token-row stride in bf16 (160 B; b64/b128 aligned)

// ---------------------------------------------------------------------------
// Fused encoder + MFMA gravity, transposed dataflow (R6).
// State p lives in "Bp-layout": lane(quad,col) holds token=col, dims quad*4+r.
// Per iteration:
//   S^T = Aaug . Paug   : A-operand = augmented attractors (CONSTANT regs),
//                         B-operand = (p, p^2) interleaved — built in-lane.
//                         C-layout: lane holds a=16i+quad*4+r for token=col.
//   w = rcp(S^T + |a|^2) elementwise; ONE LDS round-trip to B-frag layout.
//   F^T  = A2^T . W      (A-operand constant)  -> C-layout == Bp-layout: the
//   F2^T = Ones . W      (wsum, no shuffles)      update needs NO conversion.
// Only per-iter LDS: 4x ds_write_b64 + 2x ds_read_b128 (one drain).
// launch_bounds(256,1): no VGPR cap — (256,4) caused 68 MB spill in R3.
// ---------------------------------------------------------------------------
__global__ __launch_bounds__(256, 1)
void k_enc_grav(const float* __restrict__ x, const float* __restrict__ w1,
                const float* __restrict__ b1, const float* __restrict__ w2,
                const float* __restrict__ b2, const float* __restrict__ att,
                float* __restrict__ ws)
{
    __shared__ __align__(16) char smem[4 * 64 * (HID + 1) * 4];   // 17408 B
    float  (*hred)[64][HID + 1] = (float(*)[64][HID + 1])smem;
    __bf16* Wl = (__bf16*)smem;   // 4 waves * 16 tokens * WTS bf16 = 10240 B

    const int tid  = threadIdx.x;
    const int wave = tid >> 6, lane = tid & 63;
    const int quad = lane >> 4, col = lane & 15;
    const int tok0 = blockIdx.x * 64;

    // ---- encoder stage 1: partial h; chunks 76/76/76/72 (16B-aligned) ----
    {
        const int tl = tid & 63;        // local token
        const int ck = tid >> 6;        // chunk id (wave-uniform -> w1 s_load)
        const int base = ck * 76;
        const float* xrow = x + (size_t)(tok0 + tl) * IND + base;
        float h[HID];
        #pragma unroll
        for (int j = 0; j < HID; ++j) h[j] = 0.f;
        #pragma unroll 6
        for (int i = 0; i < 18; ++i) {
            f32x4 xv = *(const f32x4*)(xrow + i * 4);
            const float* wr = w1 + (base + i * 4) * HID;
            #pragma unroll
            for (int c = 0; c < 4; ++c)
                #pragma unroll
                for (int j = 0; j < HID; ++j)
                    h[j] = fmaf(xv[c], wr[c * HID + j], h[j]);
        }
        if (ck < 3) {                   // wave-uniform branch: 19th float4
            f32x4 xv = *(const f32x4*)(xrow + 72);
            const float* wr = w1 + (base + 72) * HID;
            #pragma unroll
            for (int c = 0; c < 4; ++c)
                #pragma unroll
                for (int j = 0; j < HID; ++j)
                    h[j] = fmaf(xv[c], wr[c * HID + j], h[j]);
        }
        #pragma unroll
        for (int j = 0; j < HID; ++j) hred[ck][tl][j] = h[j];
    }
    __syncthreads();
    // ---- encoder stage 2: reduce chunks, +b1, relu ----
    {
        const int tl = tid & 63;
        const int jg = (tid >> 6) * 4;
        #pragma unroll
        for (int jj = 0; jj < 4; ++jj) {
            const int j = jg + jj;
            float s = (hred[0][tl][j] + hred[1][tl][j]) +
                      (hred[2][tl][j] + hred[3][tl][j]);
            hred[0][tl][j] = fmaxf(s + b1[j], 0.f);
        }
    }
    __syncthreads();

    // ---- encoder stage 3: p directly in Bp-layout:
    //      lane(quad,col) <- p[token=col][dims quad*4 .. quad*4+3] ----
    f32x4 p;
    {
        const float* hrow = &hred[0][wave * 16 + col][0];
        f32x4 acc = *(const f32x4*)(b2 + quad * 4);
        #pragma unroll
        for (int j = 0; j < HID; ++j) {
            float hj = hrow[j];
            f32x4 wv = *(const f32x4*)(w2 + j * LAT + quad * 4);
            #pragma unroll
            for (int r = 0; r < 4; ++r) acc[r] = fmaf(hj, wv[r], acc[r]);
        }
        p = acc;
    }
    __syncthreads();   // hred dead; Wl may now overwrite it

    // ---- constant fragments (built once, live in registers all 20 iters) ----
    const f32x4 zf = {0.f, 0.f, 0.f, 0.f};
    bf16x8 ones8;
    #pragma unroll
    for (int e = 0; e < 8; ++e) ones8[e] = (__bf16)1.0f;

    // Aaug for S^T: A[m=a(16i+col)][k]: k even -> -2*att[a][quad*4+k/2], odd -> 1
    bf16x8 aS[4];
    #pragma unroll
    for (int i = 0; i < 4; ++i) {
        f32x4 av = *(const f32x4*)(att + (16 * i + col) * LAT + quad * 4);
        #pragma unroll
        for (int m = 0; m < 4; ++m) {
            aS[i][2 * m]     = (__bf16)(-2.0f * av[m]);
            aS[i][2 * m + 1] = (__bf16)1.0f;
        }
    }
    // |a|^2 redistributed to C-layout positions: sanv[i][r] = |att[16i+quad*4+r]|^2
    f32x4 sanv[4];
    {
        float nrm[4];
        #pragma unroll
        for (int i = 0; i < 4; ++i) {
            const float* ar = att + (16 * i + col) * LAT;
            float s = 0.f;
            #pragma unroll
            for (int k = 0; k < LAT; ++k) s = fmaf(ar[k], ar[k], s);
            nrm[i] = s;
        }
        #pragma unroll
        for (int i = 0; i < 4; ++i)
            #pragma unroll
            for (int r = 0; r < 4; ++r)
                sanv[i][r] = __shfl(nrm[i], 16 * quad + quad * 4 + r);
    }
    // A2^T for F^T: A[m=d=col][k=a=32h+quad*8+j]
    bf16x8 aF[2];
    #pragma unroll
    for (int h = 0; h < 2; ++h)
        #pragma unroll
        for (int j = 0; j < 8; ++j)
            aF[h][j] = (__bf16)att[(32 * h + quad * 8 + j) * LAT + col];

    __bf16* myW = Wl + wave * 16 * WTS;   // token-major rows, 80 bf16 each

    float cd = 0.f;
    #pragma unroll 1
    for (int it = 0; it < NITER; ++it) {
        // B-frag of Paug: token=col, k=quad*8+j: even->p[dim], odd->p^2 (in-lane)
        bf16x8 bp;
        #pragma unroll
        for (int m = 0; m < 4; ++m) {
            float v = p[m];
            bp[2 * m]     = (__bf16)v;
            bp[2 * m + 1] = (__bf16)(v * v);
        }
        f32x4 sf[4];
        #pragma unroll
        for (int i = 0; i < 4; ++i)
            sf[i] = __builtin_amdgcn_mfma_f32_16x16x32_bf16(aS[i], bp, zf, 0, 0, 0);

        // w = 1/d2 ; d2 = (pn - 2 p.a) + |a|^2  — all elementwise, no shuffles
        #pragma unroll
        for (int i = 0; i < 4; ++i) {
            f32x4 s = sf[i];
            bf16x4 wp;
            #pragma unroll
            for (int r = 0; r < 4; ++r)
                wp[r] = (__bf16)__builtin_amdgcn_rcpf(s[r] + sanv[i][r]);
            // token row col, attractors 16i+quad*4 .. +3  (8B-aligned)
            *(bf16x4*)(myW + col * WTS + 16 * i + quad * 4) = wp;
        }
        // B-frags of W: token=col, a = 32h + quad*8 + j  (16B-aligned)
        bf16x8 bw0 = *(bf16x8*)(myW + col * WTS + quad * 8);
        bf16x8 bw1 = *(bf16x8*)(myW + col * WTS + 32 + quad * 8);

        f32x4 F  = __builtin_amdgcn_mfma_f32_16x16x32_bf16(aF[0], bw0, zf, 0, 0, 0);
        F  = __builtin_amdgcn_mfma_f32_16x16x32_bf16(aF[1], bw1, F,  0, 0, 0);
        f32x4 F2 = __builtin_amdgcn_mfma_f32_16x16x32_bf16(ones8, bw0, zf, 0, 0, 0);
        F2 = __builtin_amdgcn_mfma_f32_16x16x32_bf16(ones8, bw1, F2, 0, 0, 0);

        // update: p = p*(1 - 0.1*G*wsum) + 0.1*G*F   (F^T C-layout == Bp-layout)
        const bool last = (it == NITER - 1);
        #pragma unroll
        for (int r = 0; r < 4; ++r) {
            float np = fmaf(p[r], fmaf(F2[r], -0.1f * GRAV, 1.0f),
                            (0.1f * GRAV) * F[r]);
            if (last) { float d = np - p[r]; cd = fmaf(d, d, cd); }
            p[r] = np;
        }
    }

    // ---- reductions ----
    // field: sum over this wave's 16 tokens (col-lanes) per (quad, r)
    f32x4 fs = p;
    #pragma unroll
    for (int m = 1; m <= 8; m <<= 1)
        #pragma unroll
        for (int r = 0; r < 4; ++r) fs[r] += __shfl_xor(fs[r], m);
    const int b = blockIdx.x >> 5;   // 32 blocks (64 tokens) per batch row
    if (col == 0) {
        #pragma unroll
        for (int r = 0; r < 4; ++r)
            atomicAdd(ws + WS_FIELD + b * LAT + quad * 4 + r, fs[r]);
    }

    float c2 = cd;
    c2 += __shfl_xor(c2, 1);  c2 += __shfl_xor(c2, 2);  c2 += __shfl_xor(c2, 4);
    c2 += __shfl_xor(c2, 8);  c2 += __shfl_xor(c2, 16); c2 += __shfl_xor(c2, 32);
    if (lane == 0) atomicAdd(ws + WS_CHG, c2);
}

// ---------------------------------------------------------------------------
// Kernel 2: finalize — one block per batch row (32 blocks).
// ---------------------------------------------------------------------------
__global__ __launch_bounds__(512)
void k_finalize(const float* __restrict__ dw1, const float* __restrict__ db1,
                const float* __restrict__ dw2, const float* __restrict__ db2,
                const float* __restrict__ mw,  const float* __restrict__ mb,
                float* __restrict__ ws, float* __restrict__ out)
{
    __shared__ float sf[LAT];
    __shared__ float sh[HID];
    const int b = blockIdx.x, t = threadIdx.x;
    if (t < LAT) {
        float f = ws[WS_FIELD + b * LAT + t] * (1.f / SS);
        sf[t] = f;
        out[OFF_FIELD + b * LAT + t] = f;
    }
    __syncthreads();
    if (t < HID) {
        float a = db1[t];
        #pragma unroll
        for (int d = 0; d < LAT; ++d) a = fmaf(sf[d], dw1[d * HID + t], a);
        sh[t] = fmaxf(a, 0.f);
    }
    if (t == 32) {
        float a = mb[0];
        #pragma unroll
        for (int d = 0; d < LAT; ++d) a = fmaf(sf[d], mw[d], a);
        out[OFF_MASS + b] = 1.f / (1.f + expf(-a));
    }
    if (b == 0 && t == 33) out[OFF_CHG] = sqrtf(ws[WS_CHG]);
    __syncthreads();
    if (t < IND) {
        float a = db2[t];
        #pragma unroll
        for (int j = 0; j < HID; ++j) a = fmaf(sh[j], dw2[j * IND + t], a);
        ws[WS_REC + b * IND + t] = a;
    }
}

// ---------------------------------------------------------------------------
// Kernel 3: broadcast rec[b][300] -> out[b][s][300]; row from L1/L2, NT stores.
// ---------------------------------------------------------------------------
#define CHUNK 8192
#define CPB   (SS * IND / CHUNK)    // 75
__global__ __launch_bounds__(256)
void k_broadcast(const float* __restrict__ ws, float* __restrict__ out)
{
    const int b = blockIdx.x / CPB;
    const int c = blockIdx.x % CPB;
    const float* row = ws + WS_REC + b * IND;
    f32x4* o = (f32x4*)(out + OFF_REC + (size_t)b * (SS * IND) + (size_t)c * CHUNK);
    #pragma unroll
    for (int i = 0; i < CHUNK / 4 / 256; ++i) {
        const int o4 = i * 256 + threadIdx.x;
        const int r  = (c * CHUNK + o4 * 4) % IND;   // r % 4 == 0
        f32x4 v = *(const f32x4*)(row + r);
        __builtin_nontemporal_store(v, o + o4);
    }
}

extern "C" void kernel_launch(void* const* d_in, const int* in_sizes, int n_in,
                              void* d_out, int out_size, void* d_ws, size_t ws_size,
                              hipStream_t stream)
{
    const float* x   = (const float*)d_in[0];
    const float* ew1 = (const float*)d_in[1];
    const float* eb1 = (const float*)d_in[2];
    const float* ew2 = (const float*)d_in[3];
    const float* eb2 = (const float*)d_in[4];
    const float* att = (const float*)d_in[5];
    const float* dw1 = (const float*)d_in[6];
    const float* db1 = (const float*)d_in[7];
    const float* dw2 = (const float*)d_in[8];
    const float* db2 = (const float*)d_in[9];
    const float* mw  = (const float*)d_in[10];
    const float* mb  = (const float*)d_in[11];
    float* out = (float*)d_out;
    float* ws  = (float*)d_ws;

    (void)hipMemsetAsync(ws, 0, (WS_CHG + 1) * sizeof(float), stream);
    k_enc_grav<<<BB * SS / 64, 256, 0, stream>>>(x, ew1, eb1, ew2, eb2, att, ws);
    k_finalize<<<BB, 512, 0, stream>>>(dw1, db1, dw2, db2, mw, mb, ws, out);
    k_broadcast<<<BB * CPB, 256, 0, stream>>>(ws, out);
}